// Round 1
// baseline (1465.902 us; speedup 1.0000x reference)
//
#include <hip/hip_runtime.h>

// AdaptiveAngleConv: y[a,b,co,h,w] = bias[co] + sum_{ci,t} W[co,ci,perm_a[t]] * xtap_t
// Round 1: fp32 direct conv, LDS-tiled, 4 angles + 2 couts per thread.

#define CIN 64
#define COUT 64
#define HH 128
#define WW 128
#define NB 16
#define CI_CHUNK 8

// INV[a][s] = t such that PERMS[a][t] == s  (y_a += W[s] * xv[INV[a][s]])
__constant__ int __dummy_unused; // keep none; use constexpr below

__global__ __launch_bounds__(256) void aconv_direct_kernel(
    const float* __restrict__ x,      // [B][CIN][H][W]
    const float* __restrict__ wgt,    // [COUT][CIN][9]
    const float* __restrict__ bias,   // [COUT]
    float* __restrict__ out)          // [4][B][COUT][H][W]
{
    constexpr int INV0[9] = {0,1,2,3,4,5,6,7,8};
    constexpr int INV1[9] = {1,2,5,0,4,8,3,6,7};
    constexpr int INV2[9] = {2,5,8,1,4,7,0,3,6};
    constexpr int INV3[9] = {5,8,7,2,4,6,1,0,3};

    __shared__ float ws[2][CIN * 9];             // weights for 2 couts
    __shared__ float xs[CI_CHUNK][4][132];       // 4 rows x (128+2 halo), padded to 132

    const int tid = threadIdx.x;
    const int tx = tid & 127;     // w
    const int ty = tid >> 7;      // 0..1 (row within 2-row block)

    int bid = blockIdx.x;
    const int cog = bid & 31;     // co-group innermost -> consecutive blocks reuse x rows in L2
    bid >>= 5;
    const int h2 = bid & 63;
    const int b  = bid >> 6;
    const int h0 = h2 * 2;
    const int co0 = cog * 2;

    // Stage weights for the block's 2 couts (once).
    for (int i = tid; i < 2 * CIN * 9; i += 256) {
        const int c = i / (CIN * 9);
        const int rest = i - c * (CIN * 9);
        ws[c][rest] = wgt[(co0 + c) * (CIN * 9) + rest];
    }

    float acc[4][2];
    #pragma unroll
    for (int a = 0; a < 4; ++a)
        #pragma unroll
        for (int c = 0; c < 2; ++c) acc[a][c] = 0.f;

    const int h = h0 + ty;

    for (int ci0 = 0; ci0 < CIN; ci0 += CI_CHUNK) {
        __syncthreads();
        // Stage CI_CHUNK channels x 4 rows x 130 cols (halo'd, zero OOB).
        for (int i = tid; i < CI_CHUNK * 4 * 130; i += 256) {
            const int cl = i / 520;
            const int r  = (i - cl * 520) / 130;
            const int c  = i - cl * 520 - r * 130;
            const int gh = h0 - 1 + r;
            const int gw = c - 1;
            float v = 0.f;
            if (gh >= 0 && gh < HH && gw >= 0 && gw < WW)
                v = x[(((b * CIN) + ci0 + cl) * HH + gh) * WW + gw];
            xs[cl][r][c] = v;
        }
        __syncthreads();

        #pragma unroll
        for (int cl = 0; cl < CI_CHUNK; ++cl) {
            float xv[9];
            #pragma unroll
            for (int dh = 0; dh < 3; ++dh)
                #pragma unroll
                for (int dw = 0; dw < 3; ++dw)
                    xv[dh * 3 + dw] = xs[cl][ty + dh][tx + dw];
            const int ci = ci0 + cl;
            #pragma unroll
            for (int s = 0; s < 9; ++s) {
                const float w0 = ws[0][ci * 9 + s];
                const float w1 = ws[1][ci * 9 + s];
                acc[0][0] += w0 * xv[INV0[s]];  acc[0][1] += w1 * xv[INV0[s]];
                acc[1][0] += w0 * xv[INV1[s]];  acc[1][1] += w1 * xv[INV1[s]];
                acc[2][0] += w0 * xv[INV2[s]];  acc[2][1] += w1 * xv[INV2[s]];
                acc[3][0] += w0 * xv[INV3[s]];  acc[3][1] += w1 * xv[INV3[s]];
            }
        }
    }

    const float b0 = bias[co0];
    const float b1 = bias[co0 + 1];
    #pragma unroll
    for (int a = 0; a < 4; ++a) {
        out[(((size_t)(a * NB + b) * COUT + co0    ) * HH + h) * WW + tx] = acc[a][0] + b0;
        out[(((size_t)(a * NB + b) * COUT + co0 + 1) * HH + h) * WW + tx] = acc[a][1] + b1;
    }
}

extern "C" void kernel_launch(void* const* d_in, const int* in_sizes, int n_in,
                              void* d_out, int out_size, void* d_ws, size_t ws_size,
                              hipStream_t stream) {
    const float* x    = (const float*)d_in[0];
    const float* wgt  = (const float*)d_in[1];
    const float* bias = (const float*)d_in[2];
    float* out = (float*)d_out;

    const int blocks = NB * (HH / 2) * (COUT / 2);  // 16 * 64 * 32 = 32768
    aconv_direct_kernel<<<blocks, 256, 0, stream>>>(x, wgt, bias, out);
}

// Round 2
// 151.095 us; speedup vs baseline: 9.7019x; 9.7019x over previous
//
#include <hip/hip_runtime.h>

// AdaptiveAngleConv round 2: implicit-GEMM bf16 MFMA.
// M = 256 rotated channels (a*64+co), N = B*H*W spatial, K = 576 (t*64+ci).
// Block = 256 thr = 4 waves; wave wid = angle wid, 64 channels (2 M-frags of 32).
// Spatial tile per block: 2 rows x 64 w (N=128), staged once in LDS (all 64 ci).

#define CIN 64
#define COUT 64
#define HH 128
#define WW 128
#define NB 16

typedef short bf16x8 __attribute__((ext_vector_type(8)));
typedef float f32x16 __attribute__((ext_vector_type(16)));

__device__ __constant__ int PERMS_d[4][9] = {
  {0,1,2,3,4,5,6,7,8},
  {3,0,1,6,4,2,7,8,5},
  {6,3,0,7,4,1,8,5,2},
  {7,6,3,8,4,0,5,2,1},
};

static __device__ __forceinline__ unsigned short f2bf(float f) {
  unsigned u = __builtin_bit_cast(unsigned, f);
  unsigned r = (u + 0x7FFFu + ((u >> 16) & 1u)) >> 16;
  return (unsigned short)r;
}

// Build A_blk[kblk][m][j]: element e = kblk*2048 + m*8 + j; k = kblk*8+j;
// t = k>>6, ci = k&63, a = m>>6, co = m&63; val = W[co][ci][PERMS[a][t]].
__global__ void build_A_kernel(const float* __restrict__ wgt,
                               unsigned short* __restrict__ A) {
  const int e = blockIdx.x * 256 + threadIdx.x;  // 147456 total
  const int kblk = e >> 11;
  const int m = (e >> 3) & 255;
  const int j = e & 7;
  const int k = kblk * 8 + j;
  const int t = k >> 6;
  const int ci = k & 63;
  const int a = m >> 6, co = m & 63;
  A[e] = f2bf(wgt[(co * CIN + ci) * 9 + PERMS_d[a][t]]);
}

// LDS x-tile layout (bf16): byte(r, ci, w) = r*8576 + (ci>>3)*1072 + w*16 + (ci&7)*2
//   r in [0,4) rows h0-1..h0+2; w in [0,66) = w0-1..w0+64; slot stride 1072 (=67*16)
//   makes the 8 slots land on distinct bank groups (12*s mod 32 all distinct).
#define SLOT_STRIDE 1072
#define ROW_STRIDE  8576

__global__ __launch_bounds__(256, 2) void aconv_mfma_kernel(
    const float* __restrict__ x,              // [B][CIN][H][W] fp32
    const unsigned short* __restrict__ A,     // [72][256][8] bf16
    const float* __restrict__ bias,           // [COUT]
    float* __restrict__ out)                  // [4][B][COUT][H][W] fp32
{
  __shared__ unsigned char xs[4 * ROW_STRIDE];   // 34,304 B

  const int tid = threadIdx.x;
  const int lane = tid & 63;
  const int wid = tid >> 6;         // wave id == angle a
  const int half = lane >> 5;       // k-half within MFMA frags
  const int ln = lane & 31;

  int bid = blockIdx.x;
  const int wh = bid & 1;           // w half (0/1)
  const int hp = (bid >> 1) & 63;   // h pair
  const int b  = bid >> 7;          // batch
  const int w0 = wh * 64;
  const int h0 = hp * 2;

  // ---- stage x tile (each thread: one (r, ci) row of 66 halo'd elems) ----
  {
    const int ci = tid & 63;
    const int r  = tid >> 6;
    const int gh = h0 - 1 + r;
    const unsigned base = (unsigned)(r * ROW_STRIDE + (ci >> 3) * SLOT_STRIDE + (ci & 7) * 2);
    if (gh >= 0 && gh < HH) {
      const float* xrow = x + (((size_t)(b * CIN + ci) * HH + gh) * WW);
      {
        float v = (w0 - 1 >= 0) ? xrow[w0 - 1] : 0.f;
        *(unsigned short*)(xs + base) = f2bf(v);
      }
      #pragma unroll
      for (int q = 0; q < 16; ++q) {
        const float4 v4 = *(const float4*)(xrow + w0 + q * 4);
        *(unsigned short*)(xs + base + (unsigned)(1 + q*4 + 0) * 16) = f2bf(v4.x);
        *(unsigned short*)(xs + base + (unsigned)(1 + q*4 + 1) * 16) = f2bf(v4.y);
        *(unsigned short*)(xs + base + (unsigned)(1 + q*4 + 2) * 16) = f2bf(v4.z);
        *(unsigned short*)(xs + base + (unsigned)(1 + q*4 + 3) * 16) = f2bf(v4.w);
      }
      {
        float v = (w0 + 64 < WW) ? xrow[w0 + 64] : 0.f;
        *(unsigned short*)(xs + base + 65u * 16) = f2bf(v);
      }
    } else {
      #pragma unroll
      for (int w = 0; w < 66; ++w)
        *(unsigned short*)(xs + base + (unsigned)w * 16) = 0;
    }
  }
  __syncthreads();

  // ---- K-loop: 36 steps of K=16, no barriers ----
  const int m0 = wid * 64;
  f32x16 acc[2][4];
  #pragma unroll
  for (int mf = 0; mf < 2; ++mf)
    #pragma unroll
    for (int nf = 0; nf < 4; ++nf)
      acc[mf][nf] = (f32x16)(0.f);

  // A element base: ((kc*2 + half)*256 + m0 + mf*32 + ln)*8
  const unsigned short* Abase = A + (size_t)((half * 256) + m0 + ln) * 8;

  #pragma unroll
  for (int kc = 0; kc < 36; ++kc) {
    const int t  = kc >> 2;           // tap 0..8 (compile-time after unroll)
    const int dh = t / 3, dw = t % 3;
    const unsigned slotb = (unsigned)(((kc & 3) * 2 + half) * SLOT_STRIDE);

    bf16x8 bf[4];
    #pragma unroll
    for (int r = 0; r < 2; ++r)
      #pragma unroll
      for (int wq = 0; wq < 2; ++wq)
        bf[r*2+wq] = *(const bf16x8*)(xs + (unsigned)(r + dh) * ROW_STRIDE + slotb
                                         + (unsigned)(wq*32 + ln + dw) * 16);

    bf16x8 af[2];
    #pragma unroll
    for (int mf = 0; mf < 2; ++mf)
      af[mf] = *(const bf16x8*)(Abase + kc * 4096 + mf * 256);

    #pragma unroll
    for (int mf = 0; mf < 2; ++mf)
      #pragma unroll
      for (int nf = 0; nf < 4; ++nf)
        acc[mf][nf] = __builtin_amdgcn_mfma_f32_32x32x16_bf16(af[mf], bf[nf], acc[mf][nf], 0, 0, 0);
  }

  // ---- epilogue: bias + store ----
  // C/D: col = ln -> w, row = (g&3) + 8*(g>>2) + 4*half -> co offset within 32.
  float bv[2][16];
  #pragma unroll
  for (int mf = 0; mf < 2; ++mf)
    #pragma unroll
    for (int g = 0; g < 16; ++g) {
      const int rowc = (g & 3) + 8 * (g >> 2) + 4 * half;
      bv[mf][g] = bias[mf * 32 + rowc];
    }

  #pragma unroll
  for (int mf = 0; mf < 2; ++mf)
    #pragma unroll
    for (int r = 0; r < 2; ++r)
      #pragma unroll
      for (int wq = 0; wq < 2; ++wq) {
        const f32x16 v = acc[mf][r*2+wq];
        #pragma unroll
        for (int g = 0; g < 16; ++g) {
          const int rowc = (g & 3) + 8 * (g >> 2) + 4 * half;
          const int co = mf * 32 + rowc;
          const size_t o = ((((size_t)wid * NB + b) * COUT + co) * HH + (h0 + r)) * WW
                           + (w0 + wq * 32 + ln);
          out[o] = v[g] + bv[mf][g];
        }
      }
}

extern "C" void kernel_launch(void* const* d_in, const int* in_sizes, int n_in,
                              void* d_out, int out_size, void* d_ws, size_t ws_size,
                              hipStream_t stream) {
  const float* x    = (const float*)d_in[0];
  const float* wgt  = (const float*)d_in[1];
  const float* bias = (const float*)d_in[2];
  float* out = (float*)d_out;
  unsigned short* A = (unsigned short*)d_ws;   // 294,912 B

  build_A_kernel<<<576, 256, 0, stream>>>(wgt, A);
  aconv_mfma_kernel<<<NB * (HH/2) * (WW/64), 256, 0, stream>>>(x, A, bias, out);
}